// Round 20
// baseline (149.781 us; speedup 1.0000x reference)
//
#include <hip/hip_runtime.h>
#include <hip/hip_bf16.h>
#include <math.h>

#define TPB 128
#define WGS 32               // samples per workgroup (2 waves x 16); n % 32 == 0
#define NBLK 6
#define DNORM (1.0f / (0.001f + 0.69314718055994530942f))
#define LOG2E 1.44269504088896340736f
#define LN2   0.69314718055994530942f

typedef float  f32x4  __attribute__((ext_vector_type(4)));
typedef short  bf16x8 __attribute__((ext_vector_type(8)));

#define MFMA16(A, B, C) __builtin_amdgcn_mfma_f32_16x16x32_bf16((A), (B), (C), 0, 0, 0)
#define EXP2F(x) __builtin_amdgcn_exp2f(x)
#define LOG2F(x) __builtin_amdgcn_logf(x)

// d_ws layout (u16 units), ALL streamed from L2 by the main kernel (no LDS staging):
//   Region A: block b at b*1024:
//     W1c  [0..511]   compact: [tile4][u16][i8] = W1[i][tile*16+u]  (k<8 rows only)
//     bias f32[256] at u16 512  (b1 64 | b2 64 | b3p 128; b3 softmax-cols pre-scaled by log2e)
//   Region B: at 6144 + b*12288:
//     W2 [0..4095]    [kstep2][tile4][lane64][i8]
//     W3 [4096..12287][kstep2][tile8][lane64][i8]  (col>=124 zeroed; softmax cols (col%31<20) pre-scaled by log2e)
// UNPERMUTED fragment scheme (round-7 proven): position 16*tile + (lane&15) = real col.

__device__ __forceinline__ float leaky(float a) { return a >= 0.f ? a : 0.01f * a; }

__device__ __forceinline__ unsigned int bfbits(float f) {
    unsigned int u = __float_as_uint(f);
    return (u + 0x7fffu + ((u >> 16) & 1u)) >> 16;   // RNE to bf16 (prep only)
}

// packed bf16x2 via v_cvt_pk_bf16_f32 (RNE, matches bfbits)
__device__ __forceinline__ unsigned int pkcvt(float a, float b) {
    __hip_bfloat162 t = __float22bfloat162_rn(make_float2(a, b));
    union { __hip_bfloat162 b2; unsigned int u; } cv;
    cv.b2 = t;
    return cv.u;
}

__global__ void prep_kernel(const float* __restrict__ W1, const float* __restrict__ B1,
                            const float* __restrict__ W2, const float* __restrict__ B2,
                            const float* __restrict__ W3, const float* __restrict__ B3,
                            unsigned short* __restrict__ wsf)
{
    const int blk = blockIdx.x;
    const int tid = threadIdx.x;          // 1024 threads
    unsigned short* baseA = wsf + blk * 1024;
    unsigned short* baseB = wsf + 6144 + blk * 12288;
    const float* w1 = W1 + blk * 512;
    const float* w2 = W2 + blk * 4096;
    const float* w3 = W3 + blk * 7936;

    if (tid < 512) {          // W1 compact: [tile][u][i] = W1[i][tile*16+u]
        const int tile = tid >> 7, u = (tid >> 3) & 15, i = tid & 7;
        baseA[tid] = (unsigned short)bfbits(w1[i * 64 + tile * 16 + u]);
    }
    float* bb = reinterpret_cast<float*>(baseA + 512);
    if (tid >= 512 && tid < 576)        bb[tid - 512] = B1[blk * 64 + (tid - 512)];
    else if (tid >= 576 && tid < 640)   bb[tid - 512] = B2[blk * 64 + (tid - 576)];
    else if (tid >= 640 && tid < 768) {
        const int j = tid - 640;
        float f = 0.f;
        if (j < 124) {
            f = B3[blk * 124 + j];
            if (j % 31 < 20) f *= LOG2E;   // softmax cols pre-scaled for exp2
        }
        bb[128 + j] = f;
    }

    for (int e = tid; e < 4096; e += 1024) {
        const int ks = e >> 11, tile = (e >> 9) & 3, lane = (e >> 3) & 63, i = e & 7;
        const int k = ks * 32 + (lane >> 4) * 8 + i, col = tile * 16 + (lane & 15);
        baseB[e] = (unsigned short)bfbits(w2[k * 64 + col]);
    }
    for (int e = tid; e < 8192; e += 1024) {
        const int ks = e >> 12, tile = (e >> 9) & 7, lane = (e >> 3) & 63, i = e & 7;
        const int k = ks * 32 + (lane >> 4) * 8 + i, col = tile * 16 + (lane & 15);
        float f = 0.f;
        if (col < 124) {
            f = w3[k * 124 + col];
            if (col % 31 < 20) f *= LOG2E;  // softmax cols pre-scaled for exp2
        }
        baseB[4096 + e] = (unsigned short)bfbits(f);
    }
}

__global__ __launch_bounds__(TPB, 4) void flow_kernel(
    const float* __restrict__ X, const float* __restrict__ C4,
    const unsigned short* __restrict__ WSF, float* __restrict__ JAC)
{
    // 7,936 B LDS (wave-private, bf16 o-buffer), ZERO barriers, all weights from L2
    // -> up to 16 WG/CU = 32 waves/CU
    __shared__ __align__(16) unsigned short s_o[2 * 1984];   // 2 waves x [16][124] bf16; h overlays

    const int tid   = threadIdx.x;
    const int wv    = tid >> 6;        // 0..1
    const int ln    = tid & 63;
    const int col16 = ln & 15;         // MFMA col = SAMPLE slot
    const int g     = ln >> 4;         // k-group / feature-row group / trafo slot
    const size_t smp = (size_t)blockIdx.x * WGS + wv * 16 + col16;

    unsigned short* opb = s_o + wv * 1984;   // [16][124] bf16
    unsigned short* hh  = opb;               // [16][72] bf16 (overlay, same sequencing as before)

    // ---- x state in registers (replicated across the 4 g-lanes; L1-broadcast loads)
    const float4 xa = reinterpret_cast<const float4*>(X)[smp * 2 + 0];
    const float4 xb = reinterpret_cast<const float4*>(X)[smp * 2 + 1];
    float xr0 = xa.x, xr1 = xa.y, xr2 = xa.z, xr3 = xa.w;
    float xr4 = xb.x, xr5 = xb.y, xr6 = xb.z, xr7 = xb.w;
    const float4 cvv = reinterpret_cast<const float4*>(C4)[smp];

    const int fB = g * 4;
    float jacl = 0.f;

    #pragma unroll
    for (int blk = 0; blk < NBLK; ++blk) {
        const int p  = blk >> 1;
        const int cb = (blk & 1) ^ 1;
        const int tb = blk & 1;
        const int lm = (1 << p) - 1;
        const unsigned short* wAg = WSF + blk * 1024;
        const float* biasf = reinterpret_cast<const float*>(wAg + 512);
        const unsigned short* wBg = WSF + 6144 + blk * 12288;

        // ---- conditioner gather: cd is compile-time after unroll -> plain movs
        float xcf[8];
        #pragma unroll
        for (int j = 0; j < 4; ++j) {
            const int cd = ((j >> p) << (p + 1)) | (cb << p) | (j & lm);
            float v = xr0;
            v = (cd == 1) ? xr1 : v; v = (cd == 2) ? xr2 : v; v = (cd == 3) ? xr3 : v;
            v = (cd == 4) ? xr4 : v; v = (cd == 5) ? xr5 : v; v = (cd == 6) ? xr6 : v;
            v = (cd == 7) ? xr7 : v;
            xcf[j] = v;
        }
        xcf[4] = cvv.x; xcf[5] = cvv.y; xcf[6] = cvv.z; xcf[7] = cvv.w;

        union { unsigned int u[4]; bf16x8 v; } bxh;
        #pragma unroll
        for (int q = 0; q < 4; ++q)
            bxh.u[q] = (g == 0) ? pkcvt(xcf[2 * q], xcf[2 * q + 1]) : 0u;

        // ---- L1: W1c + bias streamed from L2 (wave-coalesced 16B/lane)
        #pragma unroll
        for (int tile = 0; tile < 4; ++tile) {
            f32x4 a1 = *reinterpret_cast<const f32x4*>(biasf + tile * 16 + fB);
            const bf16x8 wh = *reinterpret_cast<const bf16x8*>(wAg + tile * 128 + col16 * 8);
            a1 = MFMA16(wh, bxh.v, a1);
            uint2 pw;
            pw.x = pkcvt(leaky(a1[0]), leaky(a1[1]));
            pw.y = pkcvt(leaky(a1[2]), leaky(a1[3]));
            *reinterpret_cast<uint2*>(&hh[col16 * 72 + tile * 16 + fB]) = pw;  // ds_write_b64
        }

        // ---- L2: 64 -> 64; W2 from L2
        f32x4 acc2[4];
        #pragma unroll
        for (int tile = 0; tile < 4; ++tile)
            acc2[tile] = *reinterpret_cast<const f32x4*>(biasf + 64 + tile * 16 + fB);
        #pragma unroll
        for (int ks = 0; ks < 2; ++ks) {
            const bf16x8 hf = *reinterpret_cast<const bf16x8*>(&hh[col16 * 72 + ks * 32 + g * 8]);
            #pragma unroll
            for (int tile = 0; tile < 4; ++tile) {
                const bf16x8 wh = *reinterpret_cast<const bf16x8*>(
                    wBg + (ks * 4 + tile) * 512 + ln * 8);
                acc2[tile] = MFMA16(wh, hf, acc2[tile]);
            }
        }
        #pragma unroll
        for (int tile = 0; tile < 4; ++tile) {
            uint2 pw;
            pw.x = pkcvt(leaky(acc2[tile][0]), leaky(acc2[tile][1]));
            pw.y = pkcvt(leaky(acc2[tile][2]), leaky(acc2[tile][3]));
            *reinterpret_cast<uint2*>(&hh[col16 * 72 + tile * 16 + fB]) = pw;
        }

        // ---- L3: 64 -> 124; W3 from L2
        f32x4 acc3[8];
        #pragma unroll
        for (int tile = 0; tile < 8; ++tile)
            acc3[tile] = *reinterpret_cast<const f32x4*>(biasf + 128 + tile * 16 + fB);
        #pragma unroll
        for (int ks = 0; ks < 2; ++ks) {
            const bf16x8 hf = *reinterpret_cast<const bf16x8*>(&hh[col16 * 72 + ks * 32 + g * 8]);
            #pragma unroll
            for (int tile = 0; tile < 8; ++tile) {
                const bf16x8 wh = *reinterpret_cast<const bf16x8*>(
                    wBg + 4096 + (ks * 8 + tile) * 512 + ln * 8);
                acc3[tile] = MFMA16(wh, hf, acc3[tile]);
            }
        }

        // ---- o transpose (wave-private LDS, bf16: pkcvt + uint2 store per tile)
        #pragma unroll
        for (int tile = 0; tile < 8; ++tile)
            if (tile * 16 + fB < 124) {
                uint2 pw;
                pw.x = pkcvt(acc3[tile][0], acc3[tile][1]);
                pw.y = pkcvt(acc3[tile][2], acc3[tile][3]);
                *reinterpret_cast<uint2*>(&opb[col16 * 124 + tile * 16 + fB]) = pw;
            }

        // ---- spline: lane = (sample col16, trafo slot g); td compile-time -> movs
        float xt[4];
        #pragma unroll
        for (int j = 0; j < 4; ++j) {
            const int td = ((j >> p) << (p + 1)) | (tb << p) | (j & lm);
            float v = xr0;
            v = (td == 1) ? xr1 : v; v = (td == 2) ? xr2 : v; v = (td == 3) ? xr3 : v;
            v = (td == 4) ? xr4 : v; v = (td == 5) ? xr5 : v; v = (td == 6) ? xr6 : v;
            v = (td == 7) ? xr7 : v;
            xt[j] = v;
        }
        const float xmn = fminf(fminf(xt[0], xt[1]), fminf(xt[2], xt[3]));
        const float xmx = fmaxf(fmaxf(xt[0], xt[1]), fmaxf(xt[2], xt[3]));
        const bool inside = (xmn >= 0.f) && (xmx <= 1.f);
        float xtv = (g == 1) ? xt[1] : xt[0];
        xtv = (g == 2) ? xt[2] : xtv;
        xtv = (g == 3) ? xt[3] : xtv;

        float ov[31];
        {
            const unsigned short* ob = opb + col16 * 124 + g * 31;
            #pragma unroll
            for (int j = 0; j < 31; ++j)
                ov[j] = __uint_as_float((unsigned int)ob[j] << 16);
        }

        // widths: softmax via exp2 (weights pre-scaled by log2e; no max-subtraction)
        float ew[10];
        #pragma unroll
        for (int k = 0; k < 10; ++k) ew[k] = EXP2F(ov[k]);
        const float sw = (((ew[0] + ew[1]) + (ew[2] + ew[3])) + ((ew[4] + ew[5]) + (ew[6] + ew[7])))
                         + (ew[8] + ew[9]);
        const float fw = 0.99f / sw;
        float Cw[11];
        Cw[0] = 0.f;
        #pragma unroll
        for (int k = 1; k <= 9; ++k) Cw[k] = Cw[k - 1] + (0.001f + ew[k - 1] * fw);
        Cw[10] = 1.0f;

        // heights
        float eh[10];
        #pragma unroll
        for (int k = 0; k < 10; ++k) eh[k] = EXP2F(ov[10 + k]);
        const float sh = (((eh[0] + eh[1]) + (eh[2] + eh[3])) + ((eh[4] + eh[5]) + (eh[6] + eh[7])))
                         + (eh[8] + eh[9]);
        const float fh = 0.99f / sh;
        float Ch[11];
        Ch[0] = 0.f;
        #pragma unroll
        for (int k = 1; k <= 9; ++k) Ch[k] = Ch[k - 1] + (0.001f + eh[k - 1] * fh);
        Ch[10] = 1.0f;

        // scan: select knot pairs + RAW derivative inputs (softplus lazily after)
        const float xin = fminf(fmaxf(xtv, 0.f), 1.f);
        float in_cw = 0.f, in_cwp1 = Cw[1], in_ch = 0.f, in_chp1 = Ch[1];
        float u_d = ov[20], u_dp1 = ov[21];
        #pragma unroll
        for (int k = 1; k < 10; ++k) {
            const bool ge = (xin >= Cw[k]);
            in_cw   = ge ? Cw[k]      : in_cw;
            in_cwp1 = ge ? Cw[k + 1]  : in_cwp1;
            in_ch   = ge ? Ch[k]      : in_ch;
            in_chp1 = ge ? Ch[k + 1]  : in_chp1;
            u_d     = ge ? ov[20 + k] : u_d;
            u_dp1   = ge ? ov[21 + k] : u_dp1;
        }
        const float in_bw = in_cwp1 - in_cw;
        const float in_h  = in_chp1 - in_ch;
        const float sp_d   = (u_d   > 15.f) ? u_d   : __logf(1.f + __expf(u_d));
        const float sp_dp1 = (u_dp1 > 15.f) ? u_dp1 : __logf(1.f + __expf(u_dp1));
        const float in_d   = (0.001f + sp_d)   * DNORM;
        const float in_dp1 = (0.001f + sp_dp1) * DNORM;

        const float th   = (xin - in_cw) / in_bw;
        const float tomt = th * (1.f - th);
        const float dl   = in_h / in_bw;
        const float nume = in_h * (dl * th * th + in_d * tomt);
        const float deno = dl + (in_d + in_dp1 - 2.f * dl) * tomt;
        const float xout = in_ch + nume / deno;
        const float omt  = 1.f - th;
        const float dnum = dl * dl * (in_dp1 * th * th + 2.f * dl * tomt + in_d * omt * omt);
        const float lad  = LN2 * (LOG2F(dnum) - 2.f * LOG2F(deno));

        const float xnew = inside ? xout : xtv;
        jacl += inside ? lad : 0.f;

        // ---- x update: 4 shuffles, targets compile-time after unroll
        #pragma unroll
        for (int j = 0; j < 4; ++j) {
            const int dj = ((j >> p) << (p + 1)) | (tb << p) | (j & lm);
            const float v = __shfl(xnew, col16 + 16 * j, 64);
            if (dj == 0) xr0 = v; else if (dj == 1) xr1 = v;
            else if (dj == 2) xr2 = v; else if (dj == 3) xr3 = v;
            else if (dj == 4) xr4 = v; else if (dj == 5) xr5 = v;
            else if (dj == 6) xr6 = v; else xr7 = v;
        }
    }

    // jac = sum over the 4 trafo-slot lanes of each sample
    jacl += __shfl_xor(jacl, 16);
    jacl += __shfl_xor(jacl, 32);
    if (ln < 16)
        JAC[(size_t)blockIdx.x * WGS + wv * 16 + ln] = jacl;
}

extern "C" void kernel_launch(void* const* d_in, const int* in_sizes, int n_in,
                              void* d_out, int out_size, void* d_ws, size_t ws_size,
                              hipStream_t stream) {
    (void)n_in; (void)ws_size;
    const float* X  = (const float*)d_in[0];
    const float* C4 = (const float*)d_in[1];
    const float* W1 = (const float*)d_in[2];
    const float* B1 = (const float*)d_in[3];
    const float* W2 = (const float*)d_in[4];
    const float* B2 = (const float*)d_in[5];
    const float* W3 = (const float*)d_in[6];
    const float* B3 = (const float*)d_in[7];
    float* out = (float*)d_out;
    unsigned short* wsf = (unsigned short*)d_ws;   // 79,872 u16 = 159,744 B used

    hipLaunchKernelGGL(prep_kernel, dim3(NBLK), dim3(1024), 0, stream,
                       W1, B1, W2, B2, W3, B3, wsf);

    const int n = in_sizes[0] / 8;                 // 262144
    hipLaunchKernelGGL(flow_kernel, dim3(n / WGS), dim3(TPB), 0, stream,
                       X, C4, wsf, out);
}

// Round 21
// 143.359 us; speedup vs baseline: 1.0448x; 1.0448x over previous
//
#include <hip/hip_runtime.h>
#include <hip/hip_bf16.h>
#include <math.h>

#define TPB 128
#define WGS 32               // samples per workgroup (2 waves x 16); n % 32 == 0
#define NBLK 6
#define DNORM (1.0f / (0.001f + 0.69314718055994530942f))
#define LOG2E 1.44269504088896340736f
#define LN2   0.69314718055994530942f

typedef float  f32x4  __attribute__((ext_vector_type(4)));
typedef short  bf16x8 __attribute__((ext_vector_type(8)));

#define MFMA16(A, B, C) __builtin_amdgcn_mfma_f32_16x16x32_bf16((A), (B), (C), 0, 0, 0)
#define EXP2F(x) __builtin_amdgcn_exp2f(x)
#define LOG2F(x) __builtin_amdgcn_logf(x)

// d_ws layout (u16 units), ALL streamed from L2 by the main kernel (no LDS staging):
//   Region A: block b at b*1024:
//     W1c  [0..511]   compact: [tile4][u16][i8] = W1[i][tile*16+u]  (k<8 rows only)
//     bias f32[256] at u16 512  (b1 64 | b2 64 | b3p 128; b3 softmax-cols pre-scaled by log2e)
//   Region B: at 6144 + b*12288:
//     W2 [0..4095]    [kstep2][tile4][lane64][i8]
//     W3 [4096..12287][kstep2][tile8][lane64][i8]  (col>=124 zeroed; softmax cols (col%31<20) pre-scaled by log2e)
// UNPERMUTED fragment scheme (round-7 proven): position 16*tile + (lane&15) = real col.

__device__ __forceinline__ float leaky(float a) { return a >= 0.f ? a : 0.01f * a; }

__device__ __forceinline__ unsigned int bfbits(float f) {
    unsigned int u = __float_as_uint(f);
    return (u + 0x7fffu + ((u >> 16) & 1u)) >> 16;   // RNE to bf16 (prep only)
}

// packed bf16x2 via v_cvt_pk_bf16_f32 (RNE, matches bfbits)
__device__ __forceinline__ unsigned int pkcvt(float a, float b) {
    __hip_bfloat162 t = __float22bfloat162_rn(make_float2(a, b));
    union { __hip_bfloat162 b2; unsigned int u; } cv;
    cv.b2 = t;
    return cv.u;
}

__global__ void prep_kernel(const float* __restrict__ W1, const float* __restrict__ B1,
                            const float* __restrict__ W2, const float* __restrict__ B2,
                            const float* __restrict__ W3, const float* __restrict__ B3,
                            unsigned short* __restrict__ wsf)
{
    const int blk = blockIdx.x;
    const int tid = threadIdx.x;          // 1024 threads
    unsigned short* baseA = wsf + blk * 1024;
    unsigned short* baseB = wsf + 6144 + blk * 12288;
    const float* w1 = W1 + blk * 512;
    const float* w2 = W2 + blk * 4096;
    const float* w3 = W3 + blk * 7936;

    if (tid < 512) {          // W1 compact: [tile][u][i] = W1[i][tile*16+u]
        const int tile = tid >> 7, u = (tid >> 3) & 15, i = tid & 7;
        baseA[tid] = (unsigned short)bfbits(w1[i * 64 + tile * 16 + u]);
    }
    float* bb = reinterpret_cast<float*>(baseA + 512);
    if (tid >= 512 && tid < 576)        bb[tid - 512] = B1[blk * 64 + (tid - 512)];
    else if (tid >= 576 && tid < 640)   bb[tid - 512] = B2[blk * 64 + (tid - 576)];
    else if (tid >= 640 && tid < 768) {
        const int j = tid - 640;
        float f = 0.f;
        if (j < 124) {
            f = B3[blk * 124 + j];
            if (j % 31 < 20) f *= LOG2E;   // softmax cols pre-scaled for exp2
        }
        bb[128 + j] = f;
    }

    for (int e = tid; e < 4096; e += 1024) {
        const int ks = e >> 11, tile = (e >> 9) & 3, lane = (e >> 3) & 63, i = e & 7;
        const int k = ks * 32 + (lane >> 4) * 8 + i, col = tile * 16 + (lane & 15);
        baseB[e] = (unsigned short)bfbits(w2[k * 64 + col]);
    }
    for (int e = tid; e < 8192; e += 1024) {
        const int ks = e >> 12, tile = (e >> 9) & 7, lane = (e >> 3) & 63, i = e & 7;
        const int k = ks * 32 + (lane >> 4) * 8 + i, col = tile * 16 + (lane & 15);
        float f = 0.f;
        if (col < 124) {
            f = w3[k * 124 + col];
            if (col % 31 < 20) f *= LOG2E;  // softmax cols pre-scaled for exp2
        }
        baseB[4096 + e] = (unsigned short)bfbits(f);
    }
}

__global__ __launch_bounds__(TPB, 3) void flow_kernel(
    const float* __restrict__ X, const float* __restrict__ C4,
    const unsigned short* __restrict__ WSF, float* __restrict__ JAC)
{
    // 15,872 B LDS (wave-private only), ZERO barriers, all weights from L2
    __shared__ __align__(16) float s_o[2 * 1984];   // 2 waves x [16][124] f32; h overlays

    const int tid   = threadIdx.x;
    const int wv    = tid >> 6;        // 0..1
    const int ln    = tid & 63;
    const int col16 = ln & 15;         // MFMA col = SAMPLE slot
    const int g     = ln >> 4;         // k-group / feature-row group / trafo slot
    const size_t smp = (size_t)blockIdx.x * WGS + wv * 16 + col16;

    float*          op = s_o + wv * 1984;                        // [16][124] f32
    unsigned short* hh = reinterpret_cast<unsigned short*>(op);  // [16][72] bf16 (overlay)

    // ---- x state in registers (replicated across the 4 g-lanes; L1-broadcast loads)
    const float4 xa = reinterpret_cast<const float4*>(X)[smp * 2 + 0];
    const float4 xb = reinterpret_cast<const float4*>(X)[smp * 2 + 1];
    float xr0 = xa.x, xr1 = xa.y, xr2 = xa.z, xr3 = xa.w;
    float xr4 = xb.x, xr5 = xb.y, xr6 = xb.z, xr7 = xb.w;
    const float4 cvv = reinterpret_cast<const float4*>(C4)[smp];

    const int fB = g * 4;
    float jacl2 = 0.f;     // accumulated in log2 units; scaled by LN2 once at the end

    #pragma unroll
    for (int blk = 0; blk < NBLK; ++blk) {
        const int p  = blk >> 1;
        const int cb = (blk & 1) ^ 1;
        const int tb = blk & 1;
        const int lm = (1 << p) - 1;
        const unsigned short* wAg = WSF + blk * 1024;
        const float* biasf = reinterpret_cast<const float*>(wAg + 512);
        const unsigned short* wBg = WSF + 6144 + blk * 12288;

        // ---- conditioner gather: cd is compile-time after unroll -> plain movs
        float xcf[8];
        #pragma unroll
        for (int j = 0; j < 4; ++j) {
            const int cd = ((j >> p) << (p + 1)) | (cb << p) | (j & lm);
            float v = xr0;
            v = (cd == 1) ? xr1 : v; v = (cd == 2) ? xr2 : v; v = (cd == 3) ? xr3 : v;
            v = (cd == 4) ? xr4 : v; v = (cd == 5) ? xr5 : v; v = (cd == 6) ? xr6 : v;
            v = (cd == 7) ? xr7 : v;
            xcf[j] = v;
        }
        xcf[4] = cvv.x; xcf[5] = cvv.y; xcf[6] = cvv.z; xcf[7] = cvv.w;

        union { unsigned int u[4]; bf16x8 v; } bxh;
        #pragma unroll
        for (int q = 0; q < 4; ++q)
            bxh.u[q] = (g == 0) ? pkcvt(xcf[2 * q], xcf[2 * q + 1]) : 0u;

        // ---- L1: W1c + bias streamed from L2 (wave-coalesced 16B/lane)
        #pragma unroll
        for (int tile = 0; tile < 4; ++tile) {
            f32x4 a1 = *reinterpret_cast<const f32x4*>(biasf + tile * 16 + fB);
            const bf16x8 wh = *reinterpret_cast<const bf16x8*>(wAg + tile * 128 + col16 * 8);
            a1 = MFMA16(wh, bxh.v, a1);
            uint2 pw;
            pw.x = pkcvt(leaky(a1[0]), leaky(a1[1]));
            pw.y = pkcvt(leaky(a1[2]), leaky(a1[3]));
            *reinterpret_cast<uint2*>(&hh[col16 * 72 + tile * 16 + fB]) = pw;  // ds_write_b64
        }

        // ---- L2: 64 -> 64; W2 from L2
        f32x4 acc2[4];
        #pragma unroll
        for (int tile = 0; tile < 4; ++tile)
            acc2[tile] = *reinterpret_cast<const f32x4*>(biasf + 64 + tile * 16 + fB);
        #pragma unroll
        for (int ks = 0; ks < 2; ++ks) {
            const bf16x8 hf = *reinterpret_cast<const bf16x8*>(&hh[col16 * 72 + ks * 32 + g * 8]);
            #pragma unroll
            for (int tile = 0; tile < 4; ++tile) {
                const bf16x8 wh = *reinterpret_cast<const bf16x8*>(
                    wBg + (ks * 4 + tile) * 512 + ln * 8);
                acc2[tile] = MFMA16(wh, hf, acc2[tile]);
            }
        }
        #pragma unroll
        for (int tile = 0; tile < 4; ++tile) {
            uint2 pw;
            pw.x = pkcvt(leaky(acc2[tile][0]), leaky(acc2[tile][1]));
            pw.y = pkcvt(leaky(acc2[tile][2]), leaky(acc2[tile][3]));
            *reinterpret_cast<uint2*>(&hh[col16 * 72 + tile * 16 + fB]) = pw;
        }

        // ---- L3: 64 -> 124; W3 from L2
        f32x4 acc3[8];
        #pragma unroll
        for (int tile = 0; tile < 8; ++tile)
            acc3[tile] = *reinterpret_cast<const f32x4*>(biasf + 128 + tile * 16 + fB);
        #pragma unroll
        for (int ks = 0; ks < 2; ++ks) {
            const bf16x8 hf = *reinterpret_cast<const bf16x8*>(&hh[col16 * 72 + ks * 32 + g * 8]);
            #pragma unroll
            for (int tile = 0; tile < 8; ++tile) {
                const bf16x8 wh = *reinterpret_cast<const bf16x8*>(
                    wBg + 4096 + (ks * 8 + tile) * 512 + ln * 8);
                acc3[tile] = MFMA16(wh, hf, acc3[tile]);
            }
        }

        // ---- o transpose (wave-private LDS)
        #pragma unroll
        for (int tile = 0; tile < 8; ++tile)
            if (tile * 16 + fB < 124)
                *reinterpret_cast<f32x4*>(&op[col16 * 124 + tile * 16 + fB]) = acc3[tile];

        // ---- spline: lane = (sample col16, trafo slot g); td compile-time -> movs
        float xt[4];
        #pragma unroll
        for (int j = 0; j < 4; ++j) {
            const int td = ((j >> p) << (p + 1)) | (tb << p) | (j & lm);
            float v = xr0;
            v = (td == 1) ? xr1 : v; v = (td == 2) ? xr2 : v; v = (td == 3) ? xr3 : v;
            v = (td == 4) ? xr4 : v; v = (td == 5) ? xr5 : v; v = (td == 6) ? xr6 : v;
            v = (td == 7) ? xr7 : v;
            xt[j] = v;
        }
        const float xmn = fminf(fminf(xt[0], xt[1]), fminf(xt[2], xt[3]));
        const float xmx = fmaxf(fmaxf(xt[0], xt[1]), fmaxf(xt[2], xt[3]));
        const bool inside = (xmn >= 0.f) && (xmx <= 1.f);
        float xtv = (g == 1) ? xt[1] : xt[0];
        xtv = (g == 2) ? xt[2] : xtv;
        xtv = (g == 3) ? xt[3] : xtv;

        float ov[31];
        {
            const float* ob = op + col16 * 124 + g * 31;
            #pragma unroll
            for (int j = 0; j < 31; ++j) ov[j] = ob[j];
        }

        // widths: softmax via exp2 (weights pre-scaled by log2e; no max-subtraction)
        float ew[10];
        #pragma unroll
        for (int k = 0; k < 10; ++k) ew[k] = EXP2F(ov[k]);
        const float sw = (((ew[0] + ew[1]) + (ew[2] + ew[3])) + ((ew[4] + ew[5]) + (ew[6] + ew[7])))
                         + (ew[8] + ew[9]);
        const float fw = 0.99f / sw;
        float Cw[11];
        Cw[0] = 0.f;
        #pragma unroll
        for (int k = 1; k <= 9; ++k) Cw[k] = Cw[k - 1] + (0.001f + ew[k - 1] * fw);
        Cw[10] = 1.0f;

        // heights
        float eh[10];
        #pragma unroll
        for (int k = 0; k < 10; ++k) eh[k] = EXP2F(ov[10 + k]);
        const float sh = (((eh[0] + eh[1]) + (eh[2] + eh[3])) + ((eh[4] + eh[5]) + (eh[6] + eh[7])))
                         + (eh[8] + eh[9]);
        const float fh = 0.99f / sh;
        float Ch[11];
        Ch[0] = 0.f;
        #pragma unroll
        for (int k = 1; k <= 9; ++k) Ch[k] = Ch[k - 1] + (0.001f + eh[k - 1] * fh);
        Ch[10] = 1.0f;

        // scan: select knot pairs + RAW derivative inputs (softplus lazily after)
        const float xin = fminf(fmaxf(xtv, 0.f), 1.f);
        float in_cw = 0.f, in_cwp1 = Cw[1], in_ch = 0.f, in_chp1 = Ch[1];
        float u_d = ov[20], u_dp1 = ov[21];
        #pragma unroll
        for (int k = 1; k < 10; ++k) {
            const bool ge = (xin >= Cw[k]);
            in_cw   = ge ? Cw[k]      : in_cw;
            in_cwp1 = ge ? Cw[k + 1]  : in_cwp1;
            in_ch   = ge ? Ch[k]      : in_ch;
            in_chp1 = ge ? Ch[k + 1]  : in_chp1;
            u_d     = ge ? ov[20 + k] : u_d;
            u_dp1   = ge ? ov[21 + k] : u_dp1;
        }
        const float in_bw = in_cwp1 - in_cw;
        const float in_h  = in_chp1 - in_ch;
        const float sp_d   = (u_d   > 15.f) ? u_d   : __logf(1.f + __expf(u_d));
        const float sp_dp1 = (u_dp1 > 15.f) ? u_dp1 : __logf(1.f + __expf(u_dp1));
        const float in_d   = (0.001f + sp_d)   * DNORM;
        const float in_dp1 = (0.001f + sp_dp1) * DNORM;

        const float th   = (xin - in_cw) / in_bw;
        const float tomt = th * (1.f - th);
        const float dl   = in_h / in_bw;
        const float nume = in_h * (dl * th * th + in_d * tomt);
        const float deno = dl + (in_d + in_dp1 - 2.f * dl) * tomt;
        const float xout = in_ch + nume / deno;
        const float omt  = 1.f - th;
        const float dnum = dl * dl * (in_dp1 * th * th + 2.f * dl * tomt + in_d * omt * omt);
        const float lad2 = LOG2F(dnum) - 2.f * LOG2F(deno);   // log2 units

        const float xnew = inside ? xout : xtv;
        jacl2 += inside ? lad2 : 0.f;

        // ---- x update: 4 shuffles, targets compile-time after unroll
        #pragma unroll
        for (int j = 0; j < 4; ++j) {
            const int dj = ((j >> p) << (p + 1)) | (tb << p) | (j & lm);
            const float v = __shfl(xnew, col16 + 16 * j, 64);
            if (dj == 0) xr0 = v; else if (dj == 1) xr1 = v;
            else if (dj == 2) xr2 = v; else if (dj == 3) xr3 = v;
            else if (dj == 4) xr4 = v; else if (dj == 5) xr5 = v;
            else if (dj == 6) xr6 = v; else xr7 = v;
        }
    }

    // jac = LN2 * sum over the 4 trafo-slot lanes of each sample
    jacl2 += __shfl_xor(jacl2, 16);
    jacl2 += __shfl_xor(jacl2, 32);
    if (ln < 16)
        JAC[(size_t)blockIdx.x * WGS + wv * 16 + ln] = jacl2 * LN2;
}

extern "C" void kernel_launch(void* const* d_in, const int* in_sizes, int n_in,
                              void* d_out, int out_size, void* d_ws, size_t ws_size,
                              hipStream_t stream) {
    (void)n_in; (void)ws_size;
    const float* X  = (const float*)d_in[0];
    const float* C4 = (const float*)d_in[1];
    const float* W1 = (const float*)d_in[2];
    const float* B1 = (const float*)d_in[3];
    const float* W2 = (const float*)d_in[4];
    const float* B2 = (const float*)d_in[5];
    const float* W3 = (const float*)d_in[6];
    const float* B3 = (const float*)d_in[7];
    float* out = (float*)d_out;
    unsigned short* wsf = (unsigned short*)d_ws;   // 79,872 u16 = 159,744 B used

    hipLaunchKernelGGL(prep_kernel, dim3(NBLK), dim3(1024), 0, stream,
                       W1, B1, W2, B2, W3, B3, wsf);

    const int n = in_sizes[0] / 8;                 // 262144
    hipLaunchKernelGGL(flow_kernel, dim3(n / WGS), dim3(TPB), 0, stream,
                       X, C4, wsf, out);
}